// Round 15
// baseline (79.520 us; speedup 1.0000x reference)
//
#include <hip/hip_runtime.h>
#include <math.h>

#define CHI 64
#define CHO 64
#define BB 4
#define HH 128
#define WW 256
#define HWSZ (HH * WW)     // 32768 px per channel plane
#define NSTEP 18           // 576 / 32
#define WROWS 9
#define WCOLS 23
#define WSTRIDE 144        // bytes per window entry (128 data + 16 pad)
#define WENTRIES (WROWS * WCOLS)   // 207

typedef float f32x4 __attribute__((ext_vector_type(4)));
typedef _Float16 f16x8 __attribute__((ext_vector_type(8)));

// Device-global weight staging (no ws_size dependence). All f16.
__device__ __attribute__((aligned(16))) ushort g_wB2[NSTEP * 4 * 64 * 8];   // [s][n][lane][8] f16
__device__ __attribute__((aligned(16))) ushort g_wOffB2[NSTEP * 2 * 64 * 8];// [s][j][lane][8] f16

__device__ __forceinline__ ushort f2h(float f) {
    _Float16 h = (_Float16)f;
    return __builtin_bit_cast(ushort, h);
}
__device__ __forceinline__ uint32_t pkh2(float a, float b) {
    return (uint32_t)f2h(a) | ((uint32_t)f2h(b) << 16);
}
__device__ __forceinline__ _Float16 hlo(uint32_t u) {
    return __builtin_bit_cast(_Float16, (ushort)(u & 0xffffu));
}
__device__ __forceinline__ _Float16 hhi(uint32_t u) {
    return __builtin_bit_cast(_Float16, (ushort)(u >> 16));
}

__global__ void prep(const float* __restrict__ weight, const float* __restrict__ w_off) {
    int idx = blockIdx.x * 256 + threadIdx.x;
    if (idx < NSTEP * 4 * 64 * 8) {
        int e = idx & 7, t = idx >> 3;
        int l = t & 63; t >>= 6;
        int n = t & 3, s = t >> 2;
        int o = n * 16 + (l & 15);
        int K = s * 32 + (l >> 4) * 8 + e;
        int kh = K >> 6, c = K & 63;
        g_wB2[idx] = f2h(weight[(o * CHI + c) * 9 + kh]);
    }
    if (idx < NSTEP * 2 * 64 * 8) {
        int e = idx & 7, t = idx >> 3;
        int l = t & 63; t >>= 6;
        int j = t & 1, s = t >> 1;
        int o = j * 16 + (l & 15);
        int K = s * 32 + (l >> 4) * 8 + e;
        int kh = K >> 6, c = K & 63;
        g_wOffB2[idx] = (o < 27) ? f2h(w_off[(o * CHI + c) * 9 + kh]) : (ushort)0;
    }
}

union U8 { uint32_t u[4]; f16x8 v; };

// Fused DCN: NCHW->window transpose + offset conv + params + gather GEMM. f16 datapath.
// Block = 4 rows x 16 cols of output px; wave wv = row hb+wv, cols wb..wb+15.
// grid = 2048 (4 batch x 32 row-tiles x 16 col-tiles).
__global__ __launch_bounds__(256, 2) void dcn_win(
    const float* __restrict__ x, const float* __restrict__ b_off,
    const float* __restrict__ bias, float* __restrict__ out)
{
    __shared__ __align__(16) char win[WENTRIES * WSTRIDE];   // 29808 B
    __shared__ union {
        float om[4][16][33];                                  // 8448 B
        struct {
            uint2 pw[4][16][9];   // packed f16 corner weights {w00|w01, w10|w11}
            uint  yx[4][16][9];   // packed int16 corner coord {y0 | x0<<16}
        } p;                                                  // 6912 B
    } sh;

    const int tid = threadIdx.x;
    const int wv = tid >> 6, l = tid & 63;
    const int lr = l & 15, lg = l >> 4;
    const int blk = blockIdx.x;
    const int b = blk >> 9;
    const int t512 = blk & 511;                 // 32 row-tiles x 16 col-tiles
    const int hb = (t512 >> 4) * 4;             // tile row base
    const int wb = (t512 & 15) * 16;            // tile col base
    const float* __restrict__ xw = x + (size_t)b * CHI * HWSZ;
    const int lgo = lg * 16;                    // byte offset of lane's 8-ch group

    // ---------------- Fused stage: NCHW f32 -> 9x23 window f16 (clamped) ----------------
    // i = cp*207 + e: entry-consecutive within a channel pair -> coalesced 23-dword runs.
    for (int i = tid; i < 32 * WENTRIES; i += 256) {
        const int cp = i / WENTRIES;            // channel pair 0..31
        const int e = i - cp * WENTRIES;
        const int r = e / WCOLS;
        const int j = e - r * WCOLS;
        const int gy = min(max(hb - 2 + r, 0), HH - 1);
        const int gx = min(max(wb - 3 + j, 0), WW - 1);
        const size_t gi = (size_t)gy * WW + gx;
        const float v0 = xw[(size_t)(2 * cp) * HWSZ + gi];
        const float v1 = xw[(size_t)(2 * cp + 1) * HWSZ + gi];
        *(uint32_t*)(win + e * WSTRIDE + cp * 4) = pkh2(v0, v1);
    }

    // Phase-1 group-0 B loads issued BEFORE the staging barrier.
    f16x8 bA[12], bB[12];
#define LOADB(BUF, G)                                                        \
    _Pragma("unroll")                                                        \
    for (int i = 0; i < 12; ++i)                                             \
        BUF[i] = *(const f16x8*)&g_wOffB2[((size_t)((G) * 12 + i) * 64 + l) * 8];

    LOADB(bA, 0)
    __syncthreads();

    // ---------------- Phase 1: offset conv (16px x 27ch) via MFMA, group-6 dbuf B ----------------
    {
        const int h = hb + wv;                  // wave's output row
        const int w = wb + lr;                  // lane's output col
        f32x4 acc0 = {0.f, 0.f, 0.f, 0.f}, acc1 = {0.f, 0.f, 0.f, 0.f};

#define COMPUTE6(BUF, G)                                                     \
    _Pragma("unroll")                                                        \
    for (int ss = 0; ss < 6; ++ss) {                                         \
        const int s = (G) * 6 + ss;                                          \
        const int kh = s >> 1, ky = kh / 3, kx = kh % 3;                     \
        const bool vld = ((unsigned)(h + ky - 1) < HH) & ((unsigned)(w + kx - 1) < WW); \
        const int e = (wv + ky + 1) * WCOLS + (lr + kx + 2);                 \
        U8 Av;                                                               \
        Av.v = *(const f16x8*)(win + e * WSTRIDE + (s & 1) * 64 + lgo);      \
        if (!vld) { Av.u[0] = 0; Av.u[1] = 0; Av.u[2] = 0; Av.u[3] = 0; }    \
        acc0 = __builtin_amdgcn_mfma_f32_16x16x32_f16(Av.v, BUF[ss * 2 + 0], acc0, 0, 0, 0); \
        acc1 = __builtin_amdgcn_mfma_f32_16x16x32_f16(Av.v, BUF[ss * 2 + 1], acc1, 0, 0, 0); \
    }

        LOADB(bB, 1)
        COMPUTE6(bA, 0)
        LOADB(bA, 2)
        COMPUTE6(bB, 1)
        COMPUTE6(bA, 2)

#pragma unroll
        for (int i = 0; i < 4; ++i) {
            sh.om[wv][lg * 4 + i][lr]      = acc0[i];
            sh.om[wv][lg * 4 + i][16 + lr] = acc1[i];
        }
    }
#undef COMPUTE6
#undef LOADB
    __syncthreads();

    // Hoisted phase-2 wf loads for taps 0 and 1 (latency covered by params compute).
    f16x8 wfc[8], wfn[8];
#pragma unroll
    for (int n = 0; n < 8; ++n)
        wfc[n] = *(const f16x8*)&g_wB2[((size_t)(0 * 8 + n) * 64 + l) * 8];
#pragma unroll
    for (int n = 0; n < 8; ++n)
        wfn[n] = *(const f16x8*)&g_wB2[((size_t)(1 * 8 + n) * 64 + l) * 8];

    // ---------------- Params: read om -> regs, sync, write pw/yx (union reuse) ----------------
    float vyr[3], vxr[3], vmr[3];
#pragma unroll
    for (int t = 0; t < 3; ++t) {
        const int kh = lg + t * 4;
        if (kh < 9) {
            vyr[t] = sh.om[wv][lr][2 * kh];
            vxr[t] = sh.om[wv][lr][2 * kh + 1];
            vmr[t] = sh.om[wv][lr][18 + kh];
        }
    }
    __syncthreads();
#pragma unroll
    for (int t = 0; t < 3; ++t) {
        const int kh = lg + t * 4;
        if (kh < 9) {
            const int h2 = hb + wv;             // px row
            const int w2 = wb + lr;             // px col
            float offy = vyr[t] + b_off[2 * kh];
            float offx = vxr[t] + b_off[2 * kh + 1];
            float mm   = vmr[t] + b_off[18 + kh];
            mm = 1.f / (1.f + __expf(-mm));
            const float sy = (float)(h2 - 1 + kh / 3) + offy;
            const float sx = (float)(w2 - 1 + kh % 3) + offx;
            const float fy = floorf(sy), fx = floorf(sx);
            const int y0 = (int)fy, x0 = (int)fx;
            const float dy = sy - fy, dx = sx - fx;
            const float wy0 = (1.f - dy) * mm, wy1 = dy * mm;
            float w00 = wy0 * (1.f - dx), w01 = wy0 * dx;
            float w10 = wy1 * (1.f - dx), w11 = wy1 * dx;
            const bool vy0 = (unsigned)y0 < HH, vy1 = (unsigned)(y0 + 1) < HH;
            const bool vx0 = (unsigned)x0 < WW, vx1 = (unsigned)(x0 + 1) < WW;
            if (!(vy0 & vx0)) w00 = 0.f;
            if (!(vy0 & vx1)) w01 = 0.f;
            if (!(vy1 & vx0)) w10 = 0.f;
            if (!(vy1 & vx1)) w11 = 0.f;
            sh.p.pw[wv][lr][kh] = make_uint2(pkh2(w00, w01), pkh2(w10, w11));
            sh.p.yx[wv][lr][kh] = (uint32_t)(uint16_t)(int16_t)y0 |
                                  ((uint32_t)(uint16_t)(int16_t)x0 << 16);
        }
    }
    __syncthreads();

    // ---------------- Phase 2: LDS gather-bilerp + MFMA, wf depth-2, unroll 3 ----------------
    f32x4 acc[4];
#pragma unroll
    for (int n = 0; n < 4; ++n) acc[n] = (f32x4){0.f, 0.f, 0.f, 0.f};

    f16x8 cc[8];
    uint2 pwc;

    // cold fallback: NCHW f32 channel-strided gather for one corner, 8 ch from CB
#define FBLOAD(DST, GI, CB)                                                  \
    {                                                                        \
        U8 t_;                                                               \
        _Pragma("unroll")                                                    \
        for (int q = 0; q < 4; ++q)                                          \
            t_.u[q] = pkh2(xw[(size_t)((CB) + 2 * q) * HWSZ + (GI)],         \
                           xw[(size_t)((CB) + 2 * q + 1) * HWSZ + (GI)]);    \
        DST = t_.v;                                                          \
    }

    // decode packed y0|x0 -> clamped corners -> window LDS offsets (uniform test) or NCHW fallback
#define GATHER(DST, YX)                                                      \
    {                                                                        \
        const int y0 = (int)(short)((YX) & 0xffffu);                         \
        const int x0 = (int)(short)((YX) >> 16);                             \
        const int cy0 = min(max(y0, 0), HH - 1), cy1 = min(max(y0 + 1, 0), HH - 1); \
        const int cx0 = min(max(x0, 0), WW - 1), cx1 = min(max(x0 + 1, 0), WW - 1); \
        const int r0 = cy0 - hb + 2, r1 = cy1 - hb + 2;                      \
        const int j0 = cx0 - wb + 3, j1 = cx1 - wb + 3;                      \
        const bool okw = ((unsigned)r0 < WROWS) & ((unsigned)r1 < WROWS) &   \
                         ((unsigned)j0 < WCOLS) & ((unsigned)j1 < WCOLS);    \
        if (__all(okw)) {                                                    \
            const int l00 = (r0 * WCOLS + j0) * WSTRIDE;                     \
            const int l01 = (r0 * WCOLS + j1) * WSTRIDE;                     \
            const int l10 = (r1 * WCOLS + j0) * WSTRIDE;                     \
            const int l11 = (r1 * WCOLS + j1) * WSTRIDE;                     \
            DST[0] = *(const f16x8*)(win + l00 + lgo);                       \
            DST[1] = *(const f16x8*)(win + l01 + lgo);                       \
            DST[2] = *(const f16x8*)(win + l10 + lgo);                       \
            DST[3] = *(const f16x8*)(win + l11 + lgo);                       \
            DST[4] = *(const f16x8*)(win + l00 + lgo + 64);                  \
            DST[5] = *(const f16x8*)(win + l01 + lgo + 64);                  \
            DST[6] = *(const f16x8*)(win + l10 + lgo + 64);                  \
            DST[7] = *(const f16x8*)(win + l11 + lgo + 64);                  \
        } else {                                                             \
            const size_t g00 = (size_t)cy0 * WW + cx0;                       \
            const size_t g01 = (size_t)cy0 * WW + cx1;                       \
            const size_t g10 = (size_t)cy1 * WW + cx0;                       \
            const size_t g11 = (size_t)cy1 * WW + cx1;                       \
            const int cb0 = lg * 8, cb1 = 32 + lg * 8;                       \
            FBLOAD(DST[0], g00, cb0)                                         \
            FBLOAD(DST[1], g01, cb0)                                         \
            FBLOAD(DST[2], g10, cb0)                                         \
            FBLOAD(DST[3], g11, cb0)                                         \
            FBLOAD(DST[4], g00, cb1)                                         \
            FBLOAD(DST[5], g01, cb1)                                         \
            FBLOAD(DST[6], g10, cb1)                                         \
            FBLOAD(DST[7], g11, cb1)                                         \
        }                                                                    \
    }

    {
        const uint32_t yx0 = sh.p.yx[wv][lr][0];
        pwc = sh.p.pw[wv][lr][0];
        GATHER(cc, yx0)
    }

#pragma unroll 3
    for (int kh = 0; kh < 9; ++kh) {
        f16x8 wfn2[8], cn[8];
        uint2 pw_n; uint32_t yx_n;
        if (kh < 7) {
#pragma unroll
            for (int n = 0; n < 8; ++n)
                wfn2[n] = *(const f16x8*)&g_wB2[((size_t)((kh + 2) * 8 + n) * 64 + l) * 8];
        }
        if (kh < 8) {
            yx_n = sh.p.yx[wv][lr][kh + 1];
            pw_n = sh.p.pw[wv][lr][kh + 1];
            GATHER(cn, yx_n)
        }
        const _Float16 w00 = hlo(pwc.x), w01 = hhi(pwc.x);
        const _Float16 w10 = hlo(pwc.y), w11 = hhi(pwc.y);
        const f16x8 W00 = {w00, w00, w00, w00, w00, w00, w00, w00};
        const f16x8 W01 = {w01, w01, w01, w01, w01, w01, w01, w01};
        const f16x8 W10 = {w10, w10, w10, w10, w10, w10, w10, w10};
        const f16x8 W11 = {w11, w11, w11, w11, w11, w11, w11, w11};

        const f16x8 A0 = cc[0] * W00 + cc[1] * W01 + cc[2] * W10 + cc[3] * W11;
        const f16x8 A1 = cc[4] * W00 + cc[5] * W01 + cc[6] * W10 + cc[7] * W11;

#pragma unroll
        for (int n = 0; n < 4; ++n)
            acc[n] = __builtin_amdgcn_mfma_f32_16x16x32_f16(A0, wfc[n], acc[n], 0, 0, 0);
#pragma unroll
        for (int n = 0; n < 4; ++n)
            acc[n] = __builtin_amdgcn_mfma_f32_16x16x32_f16(A1, wfc[4 + n], acc[n], 0, 0, 0);

        if (kh < 8) {
            pwc = pw_n;
#pragma unroll
            for (int n = 0; n < 8; ++n) { cc[n] = cn[n]; wfc[n] = wfn[n]; }
            if (kh < 7) {
#pragma unroll
                for (int n = 0; n < 8; ++n) wfn[n] = wfn2[n];
            }
        }
    }
#undef GATHER
#undef FBLOAD

    // ---------------- Epilogue: C(col=o, row=px) + bias -> out[b][o][hb+wv][wb+...] ----------------
#pragma unroll
    for (int n = 0; n < 4; ++n) {
        const int o = n * 16 + lr;
        const float bo = bias[o];
        float* op = out + (((size_t)b * CHO + o) * HH + hb + wv) * WW + wb + lg * 4;
        f32x4 r;
#pragma unroll
        for (int i = 0; i < 4; ++i) r[i] = acc[n][i] + bo;
        *(f32x4*)op = r;
    }
}

extern "C" void kernel_launch(void* const* d_in, const int* in_sizes, int n_in,
                              void* d_out, int out_size, void* d_ws, size_t ws_size,
                              hipStream_t stream) {
    const float* x      = (const float*)d_in[0];
    const float* w_off  = (const float*)d_in[1];
    const float* b_off  = (const float*)d_in[2];
    const float* weight = (const float*)d_in[3];
    const float* bias   = (const float*)d_in[4];
    float* out = (float*)d_out;

    prep<<<144, 256, 0, stream>>>(weight, w_off);
    dcn_win<<<2048, 256, 0, stream>>>(x, b_off, bias, out);
}

// Round 16
// 63.618 us; speedup vs baseline: 1.2500x; 1.2500x over previous
//
#include <hip/hip_runtime.h>
#include <math.h>

#define CHI 64
#define CHO 64
#define BB 4
#define HH 128
#define WW 256
#define HWSZ (HH * WW)     // 32768 px per channel plane
#define NSTEP 18           // 576 / 32
#define WROWS 9
#define WCOLS 23
#define WSTRIDE 144        // bytes per window entry (128 data + 16 pad)
#define WENTRIES (WROWS * WCOLS)   // 207

typedef float f32x4 __attribute__((ext_vector_type(4)));
typedef _Float16 f16x8 __attribute__((ext_vector_type(8)));

// Device-global staging (no ws_size dependence). All f16.
__device__ __attribute__((aligned(16))) ushort g_xT[BB * HWSZ * CHI];       // NHWC f16: [b*HWSZ+px][c]
__device__ __attribute__((aligned(16))) ushort g_wB2[NSTEP * 4 * 64 * 8];   // [s][n][lane][8] f16
__device__ __attribute__((aligned(16))) ushort g_wOffB2[NSTEP * 2 * 64 * 8];// [s][j][lane][8] f16

__device__ __forceinline__ ushort f2h(float f) {
    _Float16 h = (_Float16)f;
    return __builtin_bit_cast(ushort, h);
}
__device__ __forceinline__ uint32_t pkh2(float a, float b) {
    return (uint32_t)f2h(a) | ((uint32_t)f2h(b) << 16);
}
__device__ __forceinline__ _Float16 hlo(uint32_t u) {
    return __builtin_bit_cast(_Float16, (ushort)(u & 0xffffu));
}
__device__ __forceinline__ _Float16 hhi(uint32_t u) {
    return __builtin_bit_cast(_Float16, (ushort)(u >> 16));
}

// NCHW f32 -> NHWC f16 transpose; blocks 0..143 also transpose the weights (prep merged).
__global__ __launch_bounds__(256) void transform(const float* __restrict__ x,
                                                 const float* __restrict__ weight,
                                                 const float* __restrict__ w_off) {
    __shared__ ushort t[64][68];
    const int tid = threadIdx.x;

    // ---- merged prep: weight transposes (independent global->global) ----
    if (blockIdx.x < 144) {
        int idx = blockIdx.x * 256 + tid;
        if (idx < NSTEP * 4 * 64 * 8) {
            int e = idx & 7, tt = idx >> 3;
            int l = tt & 63; tt >>= 6;
            int n = tt & 3, s = tt >> 2;
            int o = n * 16 + (l & 15);
            int K = s * 32 + (l >> 4) * 8 + e;
            int kh = K >> 6, c = K & 63;
            g_wB2[idx] = f2h(weight[(o * CHI + c) * 9 + kh]);
        }
        if (idx < NSTEP * 2 * 64 * 8) {
            int e = idx & 7, tt = idx >> 3;
            int l = tt & 63; tt >>= 6;
            int j = tt & 1, s = tt >> 1;
            int o = j * 16 + (l & 15);
            int K = s * 32 + (l >> 4) * 8 + e;
            int kh = K >> 6, c = K & 63;
            g_wOffB2[idx] = (o < 27) ? f2h(w_off[(o * CHI + c) * 9 + kh]) : (ushort)0;
        }
    }

    // ---- x transpose: block = 64 px x 64 ch tile ----
    const int wv = tid >> 6, lane = tid & 63;
    const int pb = blockIdx.x * 64;
    const int b = pb >> 15;
    const int pin = pb & (HWSZ - 1);
    const float* __restrict__ xb = x + (size_t)b * CHI * HWSZ + pin;
#pragma unroll
    for (int i = 0; i < 16; ++i) {
        const int c = wv * 16 + i;
        t[lane][c] = f2h(xb[(size_t)c * HWSZ + lane]);
    }
    __syncthreads();
    const int px = tid >> 2, cb = (tid & 3) * 16;
    const uint32_t* __restrict__ row = (const uint32_t*)&t[px][cb];
    uint4 v0, v1;
    v0.x = row[0]; v0.y = row[1]; v0.z = row[2]; v0.w = row[3];
    v1.x = row[4]; v1.y = row[5]; v1.z = row[6]; v1.w = row[7];
    uint4* __restrict__ dst = (uint4*)&g_xT[(size_t)(pb + px) * CHI + cb];
    dst[0] = v0; dst[1] = v1;
}

union U8 { uint32_t u[4]; f16x8 v; };

// Fused DCN: LDS x-window + offset conv + params + gather GEMM. f16 datapath.
// Block = 4 rows x 16 cols of output px; wave wv = row hb+wv, cols wb..wb+15.
// grid = 2048 (4 batch x 32 row-tiles x 16 col-tiles).
__global__ __launch_bounds__(256, 2) void dcn_win(
    const float* __restrict__ b_off, const float* __restrict__ bias,
    float* __restrict__ out)
{
    __shared__ __align__(16) char win[WENTRIES * WSTRIDE];   // 29808 B
    __shared__ union {
        float om[4][16][33];                                  // 8448 B
        struct {
            uint2 pw[4][16][9];   // packed f16 corner weights {w00|w01, w10|w11}
            uint  yx[4][16][9];   // packed int16 corner coord {y0 | x0<<16}
        } p;                                                  // 6912 B
    } sh;

    const int tid = threadIdx.x;
    const int wv = tid >> 6, l = tid & 63;
    const int lr = l & 15, lg = l >> 4;
    const int blk = blockIdx.x;
    const int b = blk >> 9;
    const int t512 = blk & 511;                 // 32 row-tiles x 16 col-tiles
    const int hb = (t512 >> 4) * 4;             // tile row base
    const int wb = (t512 & 15) * 16;            // tile col base
    const char* __restrict__ xtb = (const char*)g_xT + (size_t)b * HWSZ * (CHI * 2);
    const int lgo = lg * 16;                    // byte offset of lane's 8-ch group

    // ---------------- Stage 9x23 window of x (clamped rows/cols) ----------------
    for (int i = tid; i < WENTRIES * 8; i += 256) {
        const int e = i >> 3, q = i & 7;
        const int r = e / WCOLS;
        const int j = e - r * WCOLS;
        const int gy = min(max(hb - 2 + r, 0), HH - 1);
        const int gx = min(max(wb - 3 + j, 0), WW - 1);
        const uint4 v = *(const uint4*)(xtb + ((size_t)(gy * WW + gx)) * (CHI * 2) + q * 16);
        *(uint4*)(win + e * WSTRIDE + q * 16) = v;
    }

    // Phase-1 group-0 B loads issued BEFORE the staging barrier.
    f16x8 bA[12], bB[12];
#define LOADB(BUF, G)                                                        \
    _Pragma("unroll")                                                        \
    for (int i = 0; i < 12; ++i)                                             \
        BUF[i] = *(const f16x8*)&g_wOffB2[((size_t)((G) * 12 + i) * 64 + l) * 8];

    LOADB(bA, 0)
    __syncthreads();

    // ---------------- Phase 1: offset conv (16px x 27ch) via MFMA, group-6 dbuf B ----------------
    {
        const int h = hb + wv;                  // wave's output row
        const int w = wb + lr;                  // lane's output col
        f32x4 acc0 = {0.f, 0.f, 0.f, 0.f}, acc1 = {0.f, 0.f, 0.f, 0.f};

#define COMPUTE6(BUF, G)                                                     \
    _Pragma("unroll")                                                        \
    for (int ss = 0; ss < 6; ++ss) {                                         \
        const int s = (G) * 6 + ss;                                          \
        const int kh = s >> 1, ky = kh / 3, kx = kh % 3;                     \
        const bool vld = ((unsigned)(h + ky - 1) < HH) & ((unsigned)(w + kx - 1) < WW); \
        const int e = (wv + ky + 1) * WCOLS + (lr + kx + 2);                 \
        U8 Av;                                                               \
        Av.v = *(const f16x8*)(win + e * WSTRIDE + (s & 1) * 64 + lgo);      \
        if (!vld) { Av.u[0] = 0; Av.u[1] = 0; Av.u[2] = 0; Av.u[3] = 0; }    \
        acc0 = __builtin_amdgcn_mfma_f32_16x16x32_f16(Av.v, BUF[ss * 2 + 0], acc0, 0, 0, 0); \
        acc1 = __builtin_amdgcn_mfma_f32_16x16x32_f16(Av.v, BUF[ss * 2 + 1], acc1, 0, 0, 0); \
    }

        LOADB(bB, 1)
        COMPUTE6(bA, 0)
        LOADB(bA, 2)
        COMPUTE6(bB, 1)
        COMPUTE6(bA, 2)

#pragma unroll
        for (int i = 0; i < 4; ++i) {
            sh.om[wv][lg * 4 + i][lr]      = acc0[i];
            sh.om[wv][lg * 4 + i][16 + lr] = acc1[i];
        }
    }
#undef COMPUTE6
#undef LOADB
    __syncthreads();

    // Hoisted phase-2 wf loads for taps 0 and 1 (latency covered by params compute).
    f16x8 wfc[8], wfn[8];
#pragma unroll
    for (int n = 0; n < 8; ++n)
        wfc[n] = *(const f16x8*)&g_wB2[((size_t)(0 * 8 + n) * 64 + l) * 8];
#pragma unroll
    for (int n = 0; n < 8; ++n)
        wfn[n] = *(const f16x8*)&g_wB2[((size_t)(1 * 8 + n) * 64 + l) * 8];

    // ---------------- Params: read om -> regs, sync, write pw/yx (union reuse) ----------------
    float vyr[3], vxr[3], vmr[3];
#pragma unroll
    for (int t = 0; t < 3; ++t) {
        const int kh = lg + t * 4;
        if (kh < 9) {
            vyr[t] = sh.om[wv][lr][2 * kh];
            vxr[t] = sh.om[wv][lr][2 * kh + 1];
            vmr[t] = sh.om[wv][lr][18 + kh];
        }
    }
    __syncthreads();
#pragma unroll
    for (int t = 0; t < 3; ++t) {
        const int kh = lg + t * 4;
        if (kh < 9) {
            const int h2 = hb + wv;             // px row
            const int w2 = wb + lr;             // px col
            float offy = vyr[t] + b_off[2 * kh];
            float offx = vxr[t] + b_off[2 * kh + 1];
            float mm   = vmr[t] + b_off[18 + kh];
            mm = 1.f / (1.f + __expf(-mm));
            const float sy = (float)(h2 - 1 + kh / 3) + offy;
            const float sx = (float)(w2 - 1 + kh % 3) + offx;
            const float fy = floorf(sy), fx = floorf(sx);
            const int y0 = (int)fy, x0 = (int)fx;
            const float dy = sy - fy, dx = sx - fx;
            const float wy0 = (1.f - dy) * mm, wy1 = dy * mm;
            float w00 = wy0 * (1.f - dx), w01 = wy0 * dx;
            float w10 = wy1 * (1.f - dx), w11 = wy1 * dx;
            const bool vy0 = (unsigned)y0 < HH, vy1 = (unsigned)(y0 + 1) < HH;
            const bool vx0 = (unsigned)x0 < WW, vx1 = (unsigned)(x0 + 1) < WW;
            if (!(vy0 & vx0)) w00 = 0.f;
            if (!(vy0 & vx1)) w01 = 0.f;
            if (!(vy1 & vx0)) w10 = 0.f;
            if (!(vy1 & vx1)) w11 = 0.f;
            sh.p.pw[wv][lr][kh] = make_uint2(pkh2(w00, w01), pkh2(w10, w11));
            sh.p.yx[wv][lr][kh] = (uint32_t)(uint16_t)(int16_t)y0 |
                                  ((uint32_t)(uint16_t)(int16_t)x0 << 16);
        }
    }
    __syncthreads();

    // ---------------- Phase 2: LDS gather-bilerp + MFMA, wf depth-2, unroll 3 ----------------
    f32x4 acc[4];
#pragma unroll
    for (int n = 0; n < 4; ++n) acc[n] = (f32x4){0.f, 0.f, 0.f, 0.f};

    const char* __restrict__ xh0 = xtb + lgo;
    const char* __restrict__ xh1 = xtb + 64 + lgo;

    f16x8 cc[8];
    uint2 pwc;

    // decode packed y0|x0 -> clamped corners -> window LDS offsets (uniform test) or g_xT fallback
#define GATHER(DST, YX)                                                      \
    {                                                                        \
        const int y0 = (int)(short)((YX) & 0xffffu);                         \
        const int x0 = (int)(short)((YX) >> 16);                             \
        const int cy0 = min(max(y0, 0), HH - 1), cy1 = min(max(y0 + 1, 0), HH - 1); \
        const int cx0 = min(max(x0, 0), WW - 1), cx1 = min(max(x0 + 1, 0), WW - 1); \
        const int r0 = cy0 - hb + 2, r1 = cy1 - hb + 2;                      \
        const int j0 = cx0 - wb + 3, j1 = cx1 - wb + 3;                      \
        const bool okw = ((unsigned)r0 < WROWS) & ((unsigned)r1 < WROWS) &   \
                         ((unsigned)j0 < WCOLS) & ((unsigned)j1 < WCOLS);    \
        if (__all(okw)) {                                                    \
            const int l00 = (r0 * WCOLS + j0) * WSTRIDE;                     \
            const int l01 = (r0 * WCOLS + j1) * WSTRIDE;                     \
            const int l10 = (r1 * WCOLS + j0) * WSTRIDE;                     \
            const int l11 = (r1 * WCOLS + j1) * WSTRIDE;                     \
            DST[0] = *(const f16x8*)(win + l00 + lgo);                       \
            DST[1] = *(const f16x8*)(win + l01 + lgo);                       \
            DST[2] = *(const f16x8*)(win + l10 + lgo);                       \
            DST[3] = *(const f16x8*)(win + l11 + lgo);                       \
            DST[4] = *(const f16x8*)(win + l00 + lgo + 64);                  \
            DST[5] = *(const f16x8*)(win + l01 + lgo + 64);                  \
            DST[6] = *(const f16x8*)(win + l10 + lgo + 64);                  \
            DST[7] = *(const f16x8*)(win + l11 + lgo + 64);                  \
        } else {                                                             \
            const int o00 = (cy0 * WW + cx0) * (CHI * 2);                    \
            const int o01 = (cy0 * WW + cx1) * (CHI * 2);                    \
            const int o10 = (cy1 * WW + cx0) * (CHI * 2);                    \
            const int o11 = (cy1 * WW + cx1) * (CHI * 2);                    \
            DST[0] = *(const f16x8*)(xh0 + o00);                             \
            DST[1] = *(const f16x8*)(xh0 + o01);                             \
            DST[2] = *(const f16x8*)(xh0 + o10);                             \
            DST[3] = *(const f16x8*)(xh0 + o11);                             \
            DST[4] = *(const f16x8*)(xh1 + o00);                             \
            DST[5] = *(const f16x8*)(xh1 + o01);                             \
            DST[6] = *(const f16x8*)(xh1 + o10);                             \
            DST[7] = *(const f16x8*)(xh1 + o11);                             \
        }                                                                    \
    }

    {
        const uint32_t yx0 = sh.p.yx[wv][lr][0];
        pwc = sh.p.pw[wv][lr][0];
        GATHER(cc, yx0)
    }

#pragma unroll 3
    for (int kh = 0; kh < 9; ++kh) {
        f16x8 wfn2[8], cn[8];
        uint2 pw_n; uint32_t yx_n;
        if (kh < 7) {
#pragma unroll
            for (int n = 0; n < 8; ++n)
                wfn2[n] = *(const f16x8*)&g_wB2[((size_t)((kh + 2) * 8 + n) * 64 + l) * 8];
        }
        if (kh < 8) {
            yx_n = sh.p.yx[wv][lr][kh + 1];
            pw_n = sh.p.pw[wv][lr][kh + 1];
            GATHER(cn, yx_n)
        }
        const _Float16 w00 = hlo(pwc.x), w01 = hhi(pwc.x);
        const _Float16 w10 = hlo(pwc.y), w11 = hhi(pwc.y);
        const f16x8 W00 = {w00, w00, w00, w00, w00, w00, w00, w00};
        const f16x8 W01 = {w01, w01, w01, w01, w01, w01, w01, w01};
        const f16x8 W10 = {w10, w10, w10, w10, w10, w10, w10, w10};
        const f16x8 W11 = {w11, w11, w11, w11, w11, w11, w11, w11};

        const f16x8 A0 = cc[0] * W00 + cc[1] * W01 + cc[2] * W10 + cc[3] * W11;
        const f16x8 A1 = cc[4] * W00 + cc[5] * W01 + cc[6] * W10 + cc[7] * W11;

#pragma unroll
        for (int n = 0; n < 4; ++n)
            acc[n] = __builtin_amdgcn_mfma_f32_16x16x32_f16(A0, wfc[n], acc[n], 0, 0, 0);
#pragma unroll
        for (int n = 0; n < 4; ++n)
            acc[n] = __builtin_amdgcn_mfma_f32_16x16x32_f16(A1, wfc[4 + n], acc[n], 0, 0, 0);

        if (kh < 8) {
            pwc = pw_n;
#pragma unroll
            for (int n = 0; n < 8; ++n) { cc[n] = cn[n]; wfc[n] = wfn[n]; }
            if (kh < 7) {
#pragma unroll
                for (int n = 0; n < 8; ++n) wfn[n] = wfn2[n];
            }
        }
    }
#undef GATHER

    // ---------------- Epilogue: C(col=o, row=px) + bias -> out[b][o][hb+wv][wb+...] ----------------
#pragma unroll
    for (int n = 0; n < 4; ++n) {
        const int o = n * 16 + lr;
        const float bo = bias[o];
        float* op = out + (((size_t)b * CHO + o) * HH + hb + wv) * WW + wb + lg * 4;
        f32x4 r;
#pragma unroll
        for (int i = 0; i < 4; ++i) r[i] = acc[n][i] + bo;
        *(f32x4*)op = r;
    }
}

extern "C" void kernel_launch(void* const* d_in, const int* in_sizes, int n_in,
                              void* d_out, int out_size, void* d_ws, size_t ws_size,
                              hipStream_t stream) {
    const float* x      = (const float*)d_in[0];
    const float* w_off  = (const float*)d_in[1];
    const float* b_off  = (const float*)d_in[2];
    const float* weight = (const float*)d_in[3];
    const float* bias   = (const float*)d_in[4];
    float* out = (float*)d_out;

    transform<<<2048, 256, 0, stream>>>(x, weight, w_off);
    dcn_win<<<2048, 256, 0, stream>>>(b_off, bias, out);
}